// Round 13
// baseline (790.555 us; speedup 1.0000x reference)
//
#include <hip/hip_runtime.h>

// ---------------- CSR build ----------------

__global__ void degree_kernel(const int* __restrict__ ei, int* __restrict__ deg, int E) {
    int e = blockIdx.x * blockDim.x + threadIdx.x;
    if (e < E) {
        int dst = ei[E + e];
        atomicAdd(&deg[dst], 1);
    }
}

// ---- hierarchical exclusive scan of deg -> offs (+ invd) ----

__global__ __launch_bounds__(512) void block_sum_kernel(
    const int* __restrict__ deg, int* __restrict__ bsum, int n)
{
    __shared__ int s[512];
    int i = blockIdx.x * 512 + threadIdx.x;
    s[threadIdx.x] = (i < n) ? deg[i] : 0;
    __syncthreads();
#pragma unroll
    for (int off = 256; off > 0; off >>= 1) {
        if (threadIdx.x < off) s[threadIdx.x] += s[threadIdx.x + off];
        __syncthreads();
    }
    if (threadIdx.x == 0) bsum[blockIdx.x] = s[0];
}

__global__ __launch_bounds__(1024) void bsum_scan_kernel(int* __restrict__ bsum, int nb) {
    __shared__ int s[1024];
    int t = threadIdx.x;
    s[t] = (t < nb) ? bsum[t] : 0;
    __syncthreads();
    for (int off = 1; off < 1024; off <<= 1) {
        int v = 0;
        if (t >= off) v = s[t - off];
        __syncthreads();
        if (t >= off) s[t] += v;
        __syncthreads();
    }
    if (t < nb) bsum[t] = (t == 0) ? 0 : s[t - 1];
}

__global__ __launch_bounds__(512) void scan_write_kernel(
    const int* __restrict__ deg, const int* __restrict__ bsum,
    int* __restrict__ offs, float* __restrict__ invd, int n, int E)
{
    __shared__ int s[512];
    int t = threadIdx.x;
    int i = blockIdx.x * 512 + t;
    int d = (i < n) ? deg[i] : 0;
    s[t] = d;
    __syncthreads();
    for (int off = 1; off < 512; off <<= 1) {
        int v = 0;
        if (t >= off) v = s[t - off];
        __syncthreads();
        if (t >= off) s[t] += v;
        __syncthreads();
    }
    if (i < n) {
        offs[i] = bsum[blockIdx.x] + s[t] - d;   // exclusive prefix
        invd[i] = 1.0f / (float)(d > 0 ? d : 1);
    }
    if (blockIdx.x == 0 && t == 0) offs[n] = E;
}

__global__ void fill_kernel(const int* __restrict__ ei, const int* __restrict__ offs,
                            int* __restrict__ cursor, int* __restrict__ csr, int E) {
    int e = blockIdx.x * blockDim.x + threadIdx.x;
    if (e < E) {
        int src = ei[e];
        int dst = ei[E + e];
        int pos = atomicAdd(&cursor[dst], 1);
        csr[offs[dst] + pos] = src;
    }
}

// ---------------- mean aggregation: one wave per node, float4 gather ----------------
// Round-12 redesign: lanes split into G = 64/(D/4) groups; group p gathers
// neighbor j+p with float4 loads (1024 B per wave-instruction vs 256 B for the
// scalar version). Two independent accumulator chains; __shfl_xor combine.

template <int D>
__global__ __launch_bounds__(256) void aggregate_kernel(
    const float* __restrict__ h, const int* __restrict__ offs,
    const int* __restrict__ csr, const float* __restrict__ invd,
    float* __restrict__ mean, int nN)
{
    constexpr int LPR = D / 4;      // lanes per row (32 for D=128, 16 for D=64)
    constexpr int G = 64 / LPR;     // neighbor groups per wave (2 or 4)
    int wid = blockIdx.x * 4 + (threadIdx.x >> 6);
    int lane = threadIdx.x & 63;
    if (wid >= nN) return;
    int o0 = offs[wid], o1 = offs[wid + 1];
    const int p = lane / LPR;
    const int col = (lane % LPR) * 4;

    float4 a0 = make_float4(0.f, 0.f, 0.f, 0.f);
    float4 a1 = make_float4(0.f, 0.f, 0.f, 0.f);
    int j = o0;
    for (; j + 2 * G <= o1; j += 2 * G) {
        int s0 = csr[j + p];
        int s1 = csr[j + G + p];
        float4 v0 = *(const float4*)(h + (size_t)s0 * D + col);
        float4 v1 = *(const float4*)(h + (size_t)s1 * D + col);
        a0.x += v0.x; a0.y += v0.y; a0.z += v0.z; a0.w += v0.w;
        a1.x += v1.x; a1.y += v1.y; a1.z += v1.z; a1.w += v1.w;
    }
    if (j + G <= o1) {
        int s0 = csr[j + p];
        float4 v0 = *(const float4*)(h + (size_t)s0 * D + col);
        a0.x += v0.x; a0.y += v0.y; a0.z += v0.z; a0.w += v0.w;
        j += G;
    }
    if (j < o1 && p < o1 - j) {      // partial group (0..G-1 neighbors left)
        int s1 = csr[j + p];
        float4 v1 = *(const float4*)(h + (size_t)s1 * D + col);
        a1.x += v1.x; a1.y += v1.y; a1.z += v1.z; a1.w += v1.w;
    }
    a0.x += a1.x; a0.y += a1.y; a0.z += a1.z; a0.w += a1.w;

    // combine the G group-partials (xor strides LPR, 2*LPR, ...)
#pragma unroll
    for (int m = LPR; m < 64; m <<= 1) {
        a0.x += __shfl_xor(a0.x, m);
        a0.y += __shfl_xor(a0.y, m);
        a0.z += __shfl_xor(a0.z, m);
        a0.w += __shfl_xor(a0.w, m);
    }

    if (lane < LPR) {
        float iv = invd[wid];
        float4 r = make_float4(a0.x * iv, a0.y * iv, a0.z * iv, a0.w * iv);
        *(float4*)(mean + (size_t)wid * D + col) = r;
    }
}

// ---------------- fused dual GEMM + bias + ReLU, W staged in LDS ----------------
// Round-12 result: LDS-W confirmed (154 us, VALUBusy 36%) but occupancy 31%
// (64KB LDS + 1024-thread blocks, grid 782 -> poor balance). This round: stage
// W in K/NS quarters (32KB for layer 1), 512-thread blocks -> 4 blocks/CU,
// grid 1563, launch_bounds(512,8) keeps VGPR<=64 (round-12 body used 64).

__device__ inline void fma4(float4& a, float s, const float4& w) {
    a.x = fmaf(s, w.x, a.x);
    a.y = fmaf(s, w.y, a.y);
    a.z = fmaf(s, w.z, a.z);
    a.w = fmaf(s, w.w, a.w);
}

template <int K, int M, int R, int NS>
__global__ __launch_bounds__(512, 8) void gemm_relu_ldsw(
    const float* __restrict__ A1, const float* __restrict__ A2,
    const float* __restrict__ wl, const float* __restrict__ wr,
    const float* __restrict__ bias, float* __restrict__ out, int nN)
{
    constexpr int KQ = K / NS;            // k-slice staged at a time
    constexpr int TXc = M / 4;            // threads per row-group
    constexpr int GROUPS = 512 / TXc;
    constexpr int ROWS = GROUPS * R;      // rows per block
    constexpr int F4 = KQ * M / 4;        // float4s per matrix slice

    __shared__ float ws[2 * KQ * M];      // [0..) = wl slice, [KQ*M..) = wr slice

    const int tid = threadIdx.x;
    const int cq = (tid % TXc) * 4;
    const int g = tid / TXc;
    const int nbase = blockIdx.x * ROWS;
    const int n0 = nbase + g * R;
    const bool full = (nbase + ROWS <= nN);

    const float4 bv = *(const float4*)(bias + cq);
    float4 acc[R];
#pragma unroll
    for (int rr = 0; rr < R; rr++) acc[rr] = bv;

#pragma unroll
    for (int s = 0; s < NS; s++) {
        __syncthreads();                   // previous slice's compute done
        const float4* wlg = (const float4*)(wl + (size_t)s * KQ * M);
        const float4* wrg = (const float4*)(wr + (size_t)s * KQ * M);
        float4* s0 = (float4*)ws;
        float4* s1 = (float4*)(ws + KQ * M);
        for (int i = tid; i < F4; i += 512) {
            s0[i] = wlg[i];
            s1[i] = wrg[i];
        }
        __syncthreads();

        const int kbase = s * KQ;
        if (full) {
            const float* __restrict__ a1p = A1 + (size_t)n0 * K + kbase;
            const float* __restrict__ a2p = A2 + (size_t)n0 * K + kbase;
            for (int kk0 = 0; kk0 < KQ; kk0 += 4) {
                float4 a1v[R], a2v[R];
#pragma unroll
                for (int rr = 0; rr < R; rr++) {
                    a1v[rr] = *(const float4*)(a1p + (size_t)rr * K + kk0);
                    a2v[rr] = *(const float4*)(a2p + (size_t)rr * K + kk0);
                }
                float4 wlv[4], wrv[4];
#pragma unroll
                for (int j = 0; j < 4; j++) {
                    wlv[j] = *(const float4*)(&ws[(kk0 + j) * M + cq]);
                    wrv[j] = *(const float4*)(&ws[KQ * M + (kk0 + j) * M + cq]);
                }
#pragma unroll
                for (int rr = 0; rr < R; rr++) {
                    fma4(acc[rr], a1v[rr].x, wlv[0]);
                    fma4(acc[rr], a1v[rr].y, wlv[1]);
                    fma4(acc[rr], a1v[rr].z, wlv[2]);
                    fma4(acc[rr], a1v[rr].w, wlv[3]);
                    fma4(acc[rr], a2v[rr].x, wrv[0]);
                    fma4(acc[rr], a2v[rr].y, wrv[1]);
                    fma4(acc[rr], a2v[rr].z, wrv[2]);
                    fma4(acc[rr], a2v[rr].w, wrv[3]);
                }
            }
        } else {
            for (int kk0 = 0; kk0 < KQ; kk0 += 4) {
                float4 wlv[4], wrv[4];
#pragma unroll
                for (int j = 0; j < 4; j++) {
                    wlv[j] = *(const float4*)(&ws[(kk0 + j) * M + cq]);
                    wrv[j] = *(const float4*)(&ws[KQ * M + (kk0 + j) * M + cq]);
                }
#pragma unroll
                for (int rr = 0; rr < R; rr++) {
                    int n = n0 + rr;
                    if (n < nN) {
                        float4 a1 = *(const float4*)(A1 + (size_t)n * K + kbase + kk0);
                        float4 a2 = *(const float4*)(A2 + (size_t)n * K + kbase + kk0);
                        fma4(acc[rr], a1.x, wlv[0]);
                        fma4(acc[rr], a1.y, wlv[1]);
                        fma4(acc[rr], a1.z, wlv[2]);
                        fma4(acc[rr], a1.w, wlv[3]);
                        fma4(acc[rr], a2.x, wrv[0]);
                        fma4(acc[rr], a2.y, wrv[1]);
                        fma4(acc[rr], a2.z, wrv[2]);
                        fma4(acc[rr], a2.w, wrv[3]);
                    }
                }
            }
        }
    }

#pragma unroll
    for (int rr = 0; rr < R; rr++) {
        int n = n0 + rr;
        if (n < nN) {
            float4 v = acc[rr];
            v.x = fmaxf(v.x, 0.f); v.y = fmaxf(v.y, 0.f);
            v.z = fmaxf(v.z, 0.f); v.w = fmaxf(v.w, 0.f);
            *(float4*)(out + (size_t)n * M + cq) = v;
        }
    }
}

// ---------------- classifier: [N,32] @ [32,2] + bc ----------------

__global__ void classifier_kernel(const float* __restrict__ h,
                                  const float* __restrict__ wc,
                                  const float* __restrict__ bc,
                                  float* __restrict__ out, int nN) {
    int n = blockIdx.x * blockDim.x + threadIdx.x;
    if (n >= nN) return;
    float a0 = bc[0], a1 = bc[1];
    const float* row = h + (size_t)n * 32;
#pragma unroll
    for (int k = 0; k < 32; k++) {
        float v = row[k];
        a0 = fmaf(v, wc[k * 2 + 0], a0);
        a1 = fmaf(v, wc[k * 2 + 1], a1);
    }
    out[n * 2 + 0] = a0;
    out[n * 2 + 1] = a1;
}

// ---------------- launch ----------------

extern "C" void kernel_launch(void* const* d_in, const int* in_sizes, int n_in,
                              void* d_out, int out_size, void* d_ws, size_t ws_size,
                              hipStream_t stream) {
    const float* x   = (const float*)d_in[0];
    const int*   ei  = (const int*)d_in[1];   // [2,E] int32
    const float* w1l = (const float*)d_in[2];
    const float* b1l = (const float*)d_in[3];
    const float* w1r = (const float*)d_in[4];
    const float* w2l = (const float*)d_in[5];
    const float* b2l = (const float*)d_in[6];
    const float* w2r = (const float*)d_in[7];
    const float* w3l = (const float*)d_in[8];
    const float* b3l = (const float*)d_in[9];
    const float* w3r = (const float*)d_in[10];
    const float* wc  = (const float*)d_in[11];
    const float* bc  = (const float*)d_in[12];
    float* out = (float*)d_out;

    const int N = in_sizes[0] / 128;
    const int E = in_sizes[1] / 2;
    const int NB = (N + 511) / 512;           // scan blocks (<=1024)

    char* p = (char*)d_ws;
    auto alloc = [&](size_t bytes) {
        char* r = p;
        p += (bytes + 511) & ~(size_t)511;
        return r;
    };
    int*   deg    = (int*)  alloc((size_t)N * 4);
    int*   offs   = (int*)  alloc(((size_t)N + 1) * 4);
    int*   cursor = (int*)  alloc((size_t)N * 4);
    float* invd   = (float*)alloc((size_t)N * 4);
    int*   bsum   = (int*)  alloc((size_t)NB * 4);
    int*   csr    = (int*)  alloc((size_t)E * 4);
    float* mean   = (float*)alloc((size_t)N * 128 * 4);
    float* h1     = (float*)alloc((size_t)N * 128 * 4);
    float* h2     = (float*)alloc((size_t)N * 64 * 4);
    float* h3     = (float*)alloc((size_t)N * 32 * 4);

    hipMemsetAsync(deg, 0, (size_t)N * 4, stream);
    hipMemsetAsync(cursor, 0, (size_t)N * 4, stream);

    int eb = (E + 255) / 256;
    degree_kernel<<<eb, 256, 0, stream>>>(ei, deg, E);
    block_sum_kernel<<<NB, 512, 0, stream>>>(deg, bsum, N);
    bsum_scan_kernel<<<1, 1024, 0, stream>>>(bsum, NB);
    scan_write_kernel<<<NB, 512, 0, stream>>>(deg, bsum, offs, invd, N, E);
    fill_kernel<<<eb, 256, 0, stream>>>(ei, offs, cursor, csr, E);

    int ab = (N + 3) / 4;

    // rows per block = (512/(M/4)) * R = 8192/M (R=4)
    int g1 = (N + 8192 / 128 - 1) / (8192 / 128);   // 64 rows/blk  -> 1563
    int g2 = (N + 8192 / 64  - 1) / (8192 / 64);    // 128 rows/blk -> 782
    int g3 = (N + 8192 / 32  - 1) / (8192 / 32);    // 256 rows/blk -> 391

    aggregate_kernel<128><<<ab, 256, 0, stream>>>(x, offs, csr, invd, mean, N);
    gemm_relu_ldsw<128, 128, 4, 4><<<g1, 512, 0, stream>>>(mean, x, w1l, w1r, b1l, h1, N);

    aggregate_kernel<128><<<ab, 256, 0, stream>>>(h1, offs, csr, invd, mean, N);
    gemm_relu_ldsw<128, 64, 4, 4><<<g2, 512, 0, stream>>>(mean, h1, w2l, w2r, b2l, h2, N);

    aggregate_kernel<64><<<ab, 256, 0, stream>>>(h2, offs, csr, invd, mean, N);
    gemm_relu_ldsw<64, 32, 4, 4><<<g3, 512, 0, stream>>>(mean, h2, w3l, w3r, b3l, h3, N);

    classifier_kernel<<<(N + 255) / 256, 256, 0, stream>>>(h3, wc, bc, out, N);
}

// Round 14
// 687.204 us; speedup vs baseline: 1.1504x; 1.1504x over previous
//
#include <hip/hip_runtime.h>

// ---------------- CSR build ----------------

__global__ void degree_kernel(const int* __restrict__ ei, int* __restrict__ deg, int E) {
    int e = blockIdx.x * blockDim.x + threadIdx.x;
    if (e < E) {
        int dst = ei[E + e];
        atomicAdd(&deg[dst], 1);
    }
}

// ---- hierarchical exclusive scan of deg -> offs (+ invd) ----

__global__ __launch_bounds__(512) void block_sum_kernel(
    const int* __restrict__ deg, int* __restrict__ bsum, int n)
{
    __shared__ int s[512];
    int i = blockIdx.x * 512 + threadIdx.x;
    s[threadIdx.x] = (i < n) ? deg[i] : 0;
    __syncthreads();
#pragma unroll
    for (int off = 256; off > 0; off >>= 1) {
        if (threadIdx.x < off) s[threadIdx.x] += s[threadIdx.x + off];
        __syncthreads();
    }
    if (threadIdx.x == 0) bsum[blockIdx.x] = s[0];
}

__global__ __launch_bounds__(1024) void bsum_scan_kernel(int* __restrict__ bsum, int nb) {
    __shared__ int s[1024];
    int t = threadIdx.x;
    s[t] = (t < nb) ? bsum[t] : 0;
    __syncthreads();
    for (int off = 1; off < 1024; off <<= 1) {
        int v = 0;
        if (t >= off) v = s[t - off];
        __syncthreads();
        if (t >= off) s[t] += v;
        __syncthreads();
    }
    if (t < nb) bsum[t] = (t == 0) ? 0 : s[t - 1];
}

__global__ __launch_bounds__(512) void scan_write_kernel(
    const int* __restrict__ deg, const int* __restrict__ bsum,
    int* __restrict__ offs, float* __restrict__ invd, int n, int E)
{
    __shared__ int s[512];
    int t = threadIdx.x;
    int i = blockIdx.x * 512 + t;
    int d = (i < n) ? deg[i] : 0;
    s[t] = d;
    __syncthreads();
    for (int off = 1; off < 512; off <<= 1) {
        int v = 0;
        if (t >= off) v = s[t - off];
        __syncthreads();
        if (t >= off) s[t] += v;
        __syncthreads();
    }
    if (i < n) {
        offs[i] = bsum[blockIdx.x] + s[t] - d;   // exclusive prefix
        invd[i] = 1.0f / (float)(d > 0 ? d : 1);
    }
    if (blockIdx.x == 0 && t == 0) offs[n] = E;
}

__global__ void fill_kernel(const int* __restrict__ ei, const int* __restrict__ offs,
                            int* __restrict__ cursor, int* __restrict__ csr, int E) {
    int e = blockIdx.x * blockDim.x + threadIdx.x;
    if (e < E) {
        int src = ei[e];
        int dst = ei[E + e];
        int pos = atomicAdd(&cursor[dst], 1);
        csr[offs[dst] + pos] = src;
    }
}

// ---------------- mean aggregation: one wave per node, float4 gather ----------------

template <int D>
__global__ __launch_bounds__(256) void aggregate_kernel(
    const float* __restrict__ h, const int* __restrict__ offs,
    const int* __restrict__ csr, const float* __restrict__ invd,
    float* __restrict__ mean, int nN)
{
    constexpr int LPR = D / 4;      // lanes per row (32 for D=128, 16 for D=64)
    constexpr int G = 64 / LPR;     // neighbor groups per wave (2 or 4)
    int wid = blockIdx.x * 4 + (threadIdx.x >> 6);
    int lane = threadIdx.x & 63;
    if (wid >= nN) return;
    int o0 = offs[wid], o1 = offs[wid + 1];
    const int p = lane / LPR;
    const int col = (lane % LPR) * 4;

    float4 a0 = make_float4(0.f, 0.f, 0.f, 0.f);
    float4 a1 = make_float4(0.f, 0.f, 0.f, 0.f);
    int j = o0;
    for (; j + 2 * G <= o1; j += 2 * G) {
        int s0 = csr[j + p];
        int s1 = csr[j + G + p];
        float4 v0 = *(const float4*)(h + (size_t)s0 * D + col);
        float4 v1 = *(const float4*)(h + (size_t)s1 * D + col);
        a0.x += v0.x; a0.y += v0.y; a0.z += v0.z; a0.w += v0.w;
        a1.x += v1.x; a1.y += v1.y; a1.z += v1.z; a1.w += v1.w;
    }
    if (j + G <= o1) {
        int s0 = csr[j + p];
        float4 v0 = *(const float4*)(h + (size_t)s0 * D + col);
        a0.x += v0.x; a0.y += v0.y; a0.z += v0.z; a0.w += v0.w;
        j += G;
    }
    if (j < o1 && p < o1 - j) {      // partial group (0..G-1 neighbors left)
        int s1 = csr[j + p];
        float4 v1 = *(const float4*)(h + (size_t)s1 * D + col);
        a1.x += v1.x; a1.y += v1.y; a1.z += v1.z; a1.w += v1.w;
    }
    a0.x += a1.x; a0.y += a1.y; a0.z += a1.z; a0.w += a1.w;

#pragma unroll
    for (int m = LPR; m < 64; m <<= 1) {
        a0.x += __shfl_xor(a0.x, m);
        a0.y += __shfl_xor(a0.y, m);
        a0.z += __shfl_xor(a0.z, m);
        a0.w += __shfl_xor(a0.w, m);
    }

    if (lane < LPR) {
        float iv = invd[wid];
        float4 r = make_float4(a0.x * iv, a0.y * iv, a0.z * iv, a0.w * iv);
        *(float4*)(mean + (size_t)wid * D + col) = r;
    }
}

// ---------------- fused dual GEMM + bias + ReLU, W staged in LDS ----------------
// Round-13 post-mortem: __launch_bounds__(512,8) forced VGPR<=64 -> the
// a1v/a2v/acc working set (~80 VGPR) SPILLED (VGPR=32 reported, WRITE 169MB).
// Rule learned: this body needs a >=128-VGPR budget. Keep the 512-thread/
// NS-sliced geometry (4 blocks/CU potential) but bound (512,4).

__device__ inline void fma4(float4& a, float s, const float4& w) {
    a.x = fmaf(s, w.x, a.x);
    a.y = fmaf(s, w.y, a.y);
    a.z = fmaf(s, w.z, a.z);
    a.w = fmaf(s, w.w, a.w);
}

template <int K, int M, int R, int NS>
__global__ __launch_bounds__(512, 4) void gemm_relu_ldsw(
    const float* __restrict__ A1, const float* __restrict__ A2,
    const float* __restrict__ wl, const float* __restrict__ wr,
    const float* __restrict__ bias, float* __restrict__ out, int nN)
{
    constexpr int KQ = K / NS;            // k-slice staged at a time
    constexpr int TXc = M / 4;            // threads per row-group
    constexpr int GROUPS = 512 / TXc;
    constexpr int ROWS = GROUPS * R;      // rows per block
    constexpr int F4 = KQ * M / 4;        // float4s per matrix slice

    __shared__ float ws[2 * KQ * M];      // [0..) = wl slice, [KQ*M..) = wr slice

    const int tid = threadIdx.x;
    const int cq = (tid % TXc) * 4;
    const int g = tid / TXc;
    const int nbase = blockIdx.x * ROWS;
    const int n0 = nbase + g * R;
    const bool full = (nbase + ROWS <= nN);

    const float4 bv = *(const float4*)(bias + cq);
    float4 acc[R];
#pragma unroll
    for (int rr = 0; rr < R; rr++) acc[rr] = bv;

#pragma unroll
    for (int s = 0; s < NS; s++) {
        __syncthreads();                   // previous slice's compute done
        const float4* wlg = (const float4*)(wl + (size_t)s * KQ * M);
        const float4* wrg = (const float4*)(wr + (size_t)s * KQ * M);
        float4* s0 = (float4*)ws;
        float4* s1 = (float4*)(ws + KQ * M);
        for (int i = tid; i < F4; i += 512) {
            s0[i] = wlg[i];
            s1[i] = wrg[i];
        }
        __syncthreads();

        const int kbase = s * KQ;
        if (full) {
            const float* __restrict__ a1p = A1 + (size_t)n0 * K + kbase;
            const float* __restrict__ a2p = A2 + (size_t)n0 * K + kbase;
            for (int kk0 = 0; kk0 < KQ; kk0 += 4) {
                float4 a1v[R], a2v[R];
#pragma unroll
                for (int rr = 0; rr < R; rr++) {
                    a1v[rr] = *(const float4*)(a1p + (size_t)rr * K + kk0);
                    a2v[rr] = *(const float4*)(a2p + (size_t)rr * K + kk0);
                }
                float4 wlv[4], wrv[4];
#pragma unroll
                for (int j = 0; j < 4; j++) {
                    wlv[j] = *(const float4*)(&ws[(kk0 + j) * M + cq]);
                    wrv[j] = *(const float4*)(&ws[KQ * M + (kk0 + j) * M + cq]);
                }
#pragma unroll
                for (int rr = 0; rr < R; rr++) {
                    fma4(acc[rr], a1v[rr].x, wlv[0]);
                    fma4(acc[rr], a1v[rr].y, wlv[1]);
                    fma4(acc[rr], a1v[rr].z, wlv[2]);
                    fma4(acc[rr], a1v[rr].w, wlv[3]);
                    fma4(acc[rr], a2v[rr].x, wrv[0]);
                    fma4(acc[rr], a2v[rr].y, wrv[1]);
                    fma4(acc[rr], a2v[rr].z, wrv[2]);
                    fma4(acc[rr], a2v[rr].w, wrv[3]);
                }
            }
        } else {
            for (int kk0 = 0; kk0 < KQ; kk0 += 4) {
                float4 wlv[4], wrv[4];
#pragma unroll
                for (int j = 0; j < 4; j++) {
                    wlv[j] = *(const float4*)(&ws[(kk0 + j) * M + cq]);
                    wrv[j] = *(const float4*)(&ws[KQ * M + (kk0 + j) * M + cq]);
                }
#pragma unroll
                for (int rr = 0; rr < R; rr++) {
                    int n = n0 + rr;
                    if (n < nN) {
                        float4 a1 = *(const float4*)(A1 + (size_t)n * K + kbase + kk0);
                        float4 a2 = *(const float4*)(A2 + (size_t)n * K + kbase + kk0);
                        fma4(acc[rr], a1.x, wlv[0]);
                        fma4(acc[rr], a1.y, wlv[1]);
                        fma4(acc[rr], a1.z, wlv[2]);
                        fma4(acc[rr], a1.w, wlv[3]);
                        fma4(acc[rr], a2.x, wrv[0]);
                        fma4(acc[rr], a2.y, wrv[1]);
                        fma4(acc[rr], a2.z, wrv[2]);
                        fma4(acc[rr], a2.w, wrv[3]);
                    }
                }
            }
        }
    }

#pragma unroll
    for (int rr = 0; rr < R; rr++) {
        int n = n0 + rr;
        if (n < nN) {
            float4 v = acc[rr];
            v.x = fmaxf(v.x, 0.f); v.y = fmaxf(v.y, 0.f);
            v.z = fmaxf(v.z, 0.f); v.w = fmaxf(v.w, 0.f);
            *(float4*)(out + (size_t)n * M + cq) = v;
        }
    }
}

// ---------------- classifier: [N,32] @ [32,2] + bc ----------------

__global__ void classifier_kernel(const float* __restrict__ h,
                                  const float* __restrict__ wc,
                                  const float* __restrict__ bc,
                                  float* __restrict__ out, int nN) {
    int n = blockIdx.x * blockDim.x + threadIdx.x;
    if (n >= nN) return;
    float a0 = bc[0], a1 = bc[1];
    const float* row = h + (size_t)n * 32;
#pragma unroll
    for (int k = 0; k < 32; k++) {
        float v = row[k];
        a0 = fmaf(v, wc[k * 2 + 0], a0);
        a1 = fmaf(v, wc[k * 2 + 1], a1);
    }
    out[n * 2 + 0] = a0;
    out[n * 2 + 1] = a1;
}

// ---------------- launch ----------------

extern "C" void kernel_launch(void* const* d_in, const int* in_sizes, int n_in,
                              void* d_out, int out_size, void* d_ws, size_t ws_size,
                              hipStream_t stream) {
    const float* x   = (const float*)d_in[0];
    const int*   ei  = (const int*)d_in[1];   // [2,E] int32
    const float* w1l = (const float*)d_in[2];
    const float* b1l = (const float*)d_in[3];
    const float* w1r = (const float*)d_in[4];
    const float* w2l = (const float*)d_in[5];
    const float* b2l = (const float*)d_in[6];
    const float* w2r = (const float*)d_in[7];
    const float* w3l = (const float*)d_in[8];
    const float* b3l = (const float*)d_in[9];
    const float* w3r = (const float*)d_in[10];
    const float* wc  = (const float*)d_in[11];
    const float* bc  = (const float*)d_in[12];
    float* out = (float*)d_out;

    const int N = in_sizes[0] / 128;
    const int E = in_sizes[1] / 2;
    const int NB = (N + 511) / 512;           // scan blocks (<=1024)

    char* p = (char*)d_ws;
    auto alloc = [&](size_t bytes) {
        char* r = p;
        p += (bytes + 511) & ~(size_t)511;
        return r;
    };
    int*   deg    = (int*)  alloc((size_t)N * 4);
    int*   offs   = (int*)  alloc(((size_t)N + 1) * 4);
    int*   cursor = (int*)  alloc((size_t)N * 4);
    float* invd   = (float*)alloc((size_t)N * 4);
    int*   bsum   = (int*)  alloc((size_t)NB * 4);
    int*   csr    = (int*)  alloc((size_t)E * 4);
    float* mean   = (float*)alloc((size_t)N * 128 * 4);
    float* h1     = (float*)alloc((size_t)N * 128 * 4);
    float* h2     = (float*)alloc((size_t)N * 64 * 4);
    float* h3     = (float*)alloc((size_t)N * 32 * 4);

    hipMemsetAsync(deg, 0, (size_t)N * 4, stream);
    hipMemsetAsync(cursor, 0, (size_t)N * 4, stream);

    int eb = (E + 255) / 256;
    degree_kernel<<<eb, 256, 0, stream>>>(ei, deg, E);
    block_sum_kernel<<<NB, 512, 0, stream>>>(deg, bsum, N);
    bsum_scan_kernel<<<1, 1024, 0, stream>>>(bsum, NB);
    scan_write_kernel<<<NB, 512, 0, stream>>>(deg, bsum, offs, invd, N, E);
    fill_kernel<<<eb, 256, 0, stream>>>(ei, offs, cursor, csr, E);

    int ab = (N + 3) / 4;

    // rows per block = (512/(M/4)) * R = 8192/M (R=4)
    int g1 = (N + 8192 / 128 - 1) / (8192 / 128);   // 64 rows/blk  -> 1563
    int g2 = (N + 8192 / 64  - 1) / (8192 / 64);    // 128 rows/blk -> 782
    int g3 = (N + 8192 / 32  - 1) / (8192 / 32);    // 256 rows/blk -> 391

    aggregate_kernel<128><<<ab, 256, 0, stream>>>(x, offs, csr, invd, mean, N);
    gemm_relu_ldsw<128, 128, 4, 4><<<g1, 512, 0, stream>>>(mean, x, w1l, w1r, b1l, h1, N);

    aggregate_kernel<128><<<ab, 256, 0, stream>>>(h1, offs, csr, invd, mean, N);
    gemm_relu_ldsw<128, 64, 4, 4><<<g2, 512, 0, stream>>>(mean, h1, w2l, w2r, b2l, h2, N);

    aggregate_kernel<64><<<ab, 256, 0, stream>>>(h2, offs, csr, invd, mean, N);
    gemm_relu_ldsw<64, 32, 4, 2><<<g3, 512, 0, stream>>>(mean, h2, w3l, w3r, b3l, h3, N);

    classifier_kernel<<<(N + 255) / 256, 256, 0, stream>>>(h3, wc, bc, out, N);
}